// Round 4
// baseline (242.594 us; speedup 1.0000x reference)
//
#include <hip/hip_runtime.h>
#include <hip/hip_bf16.h>

typedef unsigned short u16;
typedef unsigned int   u32;

#define MM 8192
#define DD 128
#define JBLK 64            // MM/128 column blocks

using short8 = __attribute__((ext_vector_type(8))) short;
using f32x4  = __attribute__((ext_vector_type(4))) float;

__device__ __forceinline__ u16 f2bf(float f) {
  u32 u = __float_as_uint(f);
  u32 r = u + 0x7fffu + ((u >> 16) & 1u);   // RNE
  return (u16)(r >> 16);
}

// One wave per row: bf16 conversion + squared norms.
__global__ __launch_bounds__(256) void convert_kernel(
    const float* __restrict__ x, const float* __restrict__ y,
    u16* __restrict__ xb, u16* __restrict__ yb,
    float* __restrict__ sqx, float* __restrict__ sqy)
{
  const int wid  = threadIdx.x >> 6;
  const int lane = threadIdx.x & 63;
  const int row  = blockIdx.x * 4 + wid;
  const float2 vx = *(const float2*)(x + (size_t)row * DD + lane * 2);
  const float2 vy = *(const float2*)(y + (size_t)row * DD + lane * 2);
  float sx = vx.x * vx.x + vx.y * vx.y;
  float sy = vy.x * vy.x + vy.y * vy.y;
  #pragma unroll
  for (int off = 1; off < 64; off <<= 1) {
    sx += __shfl_xor(sx, off, 64);
    sy += __shfl_xor(sy, off, 64);
  }
  u32 px = (u32)f2bf(vx.x) | ((u32)f2bf(vx.y) << 16);
  u32 py = (u32)f2bf(vy.x) | ((u32)f2bf(vy.y) << 16);
  *(u32*)(xb + (size_t)row * DD + lane * 2) = px;
  *(u32*)(yb + (size_t)row * DD + lane * 2) = py;
  if (lane == 0) { sqx[row] = sx; sqy[row] = sy; }
}

// 128x128 tile / block, 4 waves 2x2, wave = 64x64.
// Sequential phases: X-dots (all 16 subtiles) then Y-dots, then joint
// epilogue. Each fragment is loaded exactly once from L2; no device
// atomics anywhere in this kernel (plain stores of per-block partials).
__global__ __launch_bounds__(256) void hsic_pair_kernel(
    const u16* __restrict__ xb, const u16* __restrict__ yb,
    const float* __restrict__ sqx, const float* __restrict__ sqy,
    float* __restrict__ s_part, float* __restrict__ t_part,
    float* __restrict__ P_part)
{
  const int i0   = blockIdx.y * 128;
  const int j0   = blockIdx.x * 128;
  const int tid  = threadIdx.x;
  const int wid  = tid >> 6;
  const int lane = tid & 63;
  const int wr   = wid >> 1;
  const int wc   = wid & 1;
  const int g    = lane >> 4;   // 0..3  (K-chunk for A/B frags, row-group for acc)
  const int c    = lane & 15;   // 0..15 (row for A-frag, col for B-frag/acc)

  const int ri = i0 + wr * 64;
  const int cj = j0 + wc * 64;

  __shared__ float lds_s[128];
  __shared__ float lds_t[128];
  __shared__ float red[4];
  if (tid < 128) { lds_s[tid] = 0.f; lds_t[tid] = 0.f; }
  __syncthreads();

  f32x4 accX[4][4];
  f32x4 accY[4][4];
  #pragma unroll
  for (int rs = 0; rs < 4; ++rs)
    #pragma unroll
    for (int cs = 0; cs < 4; ++cs) {
      accX[rs][cs] = (f32x4){0.f, 0.f, 0.f, 0.f};
      accY[rs][cs] = (f32x4){0.f, 0.f, 0.f, 0.f};
    }

  // ---- X phase: two K-halves, B residency = 8 short8 (32 VGPR) ----
  #pragma unroll
  for (int kh = 0; kh < 2; ++kh) {
    short8 b0[4], b1[4];
    #pragma unroll
    for (int cs = 0; cs < 4; ++cs) {
      const u16* p = xb + (size_t)(cj + cs * 16 + c) * DD + kh * 64 + g * 8;
      b0[cs] = *(const short8*)(p);
      b1[cs] = *(const short8*)(p + 32);
    }
    #pragma unroll
    for (int rs = 0; rs < 4; ++rs) {
      const u16* pa = xb + (size_t)(ri + rs * 16 + c) * DD + kh * 64 + g * 8;
      short8 a0 = *(const short8*)(pa);
      short8 a1 = *(const short8*)(pa + 32);
      #pragma unroll
      for (int cs = 0; cs < 4; ++cs) {
        accX[rs][cs] = __builtin_amdgcn_mfma_f32_16x16x32_bf16(a0, b0[cs], accX[rs][cs], 0, 0, 0);
        accX[rs][cs] = __builtin_amdgcn_mfma_f32_16x16x32_bf16(a1, b1[cs], accX[rs][cs], 0, 0, 0);
      }
    }
  }

  // ---- Y phase ----
  #pragma unroll
  for (int kh = 0; kh < 2; ++kh) {
    short8 b0[4], b1[4];
    #pragma unroll
    for (int cs = 0; cs < 4; ++cs) {
      const u16* p = yb + (size_t)(cj + cs * 16 + c) * DD + kh * 64 + g * 8;
      b0[cs] = *(const short8*)(p);
      b1[cs] = *(const short8*)(p + 32);
    }
    #pragma unroll
    for (int rs = 0; rs < 4; ++rs) {
      const u16* pa = yb + (size_t)(ri + rs * 16 + c) * DD + kh * 64 + g * 8;
      short8 a0 = *(const short8*)(pa);
      short8 a1 = *(const short8*)(pa + 32);
      #pragma unroll
      for (int cs = 0; cs < 4; ++cs) {
        accY[rs][cs] = __builtin_amdgcn_mfma_f32_16x16x32_bf16(a0, b0[cs], accY[rs][cs], 0, 0, 0);
        accY[rs][cs] = __builtin_amdgcn_mfma_f32_16x16x32_bf16(a1, b1[cs], accY[rs][cs], 0, 0, 0);
      }
    }
  }

  // ---- epilogue ----
  float sqxc[4], sqyc[4];
  #pragma unroll
  for (int cs = 0; cs < 4; ++cs) {
    sqxc[cs] = sqx[cj + cs * 16 + c];
    sqyc[cs] = sqy[cj + cs * 16 + c];
  }

  float p_acc = 0.f;

  #pragma unroll
  for (int rs = 0; rs < 4; ++rs) {
    const f32x4 sxr = *(const f32x4*)(sqx + ri + rs * 16 + g * 4);
    const f32x4 syr = *(const f32x4*)(sqy + ri + rs * 16 + g * 4);

    float s_acc[4] = {0.f, 0.f, 0.f, 0.f};
    float t_acc[4] = {0.f, 0.f, 0.f, 0.f};

    #pragma unroll
    for (int cs = 0; cs < 4; ++cs) {
      const int gc = cj + cs * 16 + c;
      #pragma unroll
      for (int tt = 0; tt < 4; ++tt) {
        const int gr = ri + rs * 16 + g * 4 + tt;
        float kx, ly;
        if (gr == gc) {
          kx = 1.f; ly = 1.f;   // exact diagonal (off-diagonals underflow anyway)
        } else {
          kx = __expf(2.f * accX[rs][cs][tt] - sxr[tt] - sqxc[cs]);
          ly = __expf(2.f * accY[rs][cs][tt] - syr[tt] - sqyc[cs]);
        }
        p_acc     += kx * ly;
        s_acc[tt] += kx;
        t_acc[tt] += ly;
      }
    }

    // Reduce row sums across the 16 lanes sharing g, accumulate LDS partials.
    #pragma unroll
    for (int tt = 0; tt < 4; ++tt) {
      float sv = s_acc[tt];
      float tv = t_acc[tt];
      #pragma unroll
      for (int off = 1; off < 16; off <<= 1) {
        sv += __shfl_xor(sv, off, 64);
        tv += __shfl_xor(tv, off, 64);
      }
      if (c == 0) {
        const int lrow = wr * 64 + rs * 16 + g * 4 + tt;
        atomicAdd(&lds_s[lrow], sv);   // LDS atomic (lgkm, cheap)
        atomicAdd(&lds_t[lrow], tv);
      }
    }
  }

  // Block-reduce P.
  #pragma unroll
  for (int off = 1; off < 64; off <<= 1) p_acc += __shfl_xor(p_acc, off, 64);
  if (lane == 0) red[wid] = p_acc;
  __syncthreads();

  // Plain coalesced stores of per-block partials (no device atomics).
  if (tid < 128) {
    s_part[(size_t)blockIdx.x * MM + i0 + tid] = lds_s[tid];
    t_part[(size_t)blockIdx.x * MM + i0 + tid] = lds_t[tid];
  }
  if (tid == 0)
    P_part[blockIdx.y * gridDim.x + blockIdx.x] = red[0] + red[1] + red[2] + red[3];
}

// 64 blocks x 128 threads: fold column-block partials, produce the 4 scalars.
__global__ __launch_bounds__(128) void reduce1_kernel(
    const float* __restrict__ s_part, const float* __restrict__ t_part,
    const float* __restrict__ P_part, double* __restrict__ acc)
{
  const int tid = threadIdx.x;
  const int row = blockIdx.x * 128 + tid;
  float sv = 0.f, tv = 0.f;
  for (int jb = 0; jb < JBLK; ++jb) {
    sv += s_part[(size_t)jb * MM + row];
    tv += t_part[(size_t)jb * MM + row];
  }
  float cv = sv * tv;
  float pv = (tid < 64) ? P_part[blockIdx.x * 64 + tid] : 0.f;
  #pragma unroll
  for (int off = 1; off < 64; off <<= 1) {
    sv += __shfl_xor(sv, off, 64);
    tv += __shfl_xor(tv, off, 64);
    cv += __shfl_xor(cv, off, 64);
    pv += __shfl_xor(pv, off, 64);
  }
  __shared__ float r[2][4];
  const int w = tid >> 6;
  if ((tid & 63) == 0) { r[w][0] = sv; r[w][1] = tv; r[w][2] = cv; r[w][3] = pv; }
  __syncthreads();
  if (tid == 0) {
    atomicAdd(&acc[0], (double)(r[0][0] + r[1][0]));
    atomicAdd(&acc[1], (double)(r[0][1] + r[1][1]));
    atomicAdd(&acc[2], (double)(r[0][2] + r[1][2]));
    atomicAdd(&acc[3], (double)(r[0][3] + r[1][3]));
  }
}

__global__ void reduce2_kernel(const double* __restrict__ acc,
                               float* __restrict__ out)
{
  const double m   = (double)MM;
  const double num = acc[3] - (2.0 / m) * acc[2] + (acc[0] * acc[1]) / (m * m);
  out[0] = (float)(num / ((m - 1.0) * (m - 1.0)));
}

extern "C" void kernel_launch(void* const* d_in, const int* in_sizes, int n_in,
                              void* d_out, int out_size, void* d_ws, size_t ws_size,
                              hipStream_t stream) {
  const float* x = (const float*)d_in[0];
  const float* y = (const float*)d_in[1];

  char* ws = (char*)d_ws;
  u16*    xb     = (u16*)ws;                                        // 2 MB
  u16*    yb     = (u16*)(ws + (size_t)2 * 1024 * 1024);            // 2 MB
  float*  sqx    = (float*)(ws + (size_t)4 * 1024 * 1024);          // 32 KB
  float*  sqy    = sqx + MM;                                        // 32 KB
  float*  s_part = sqy + MM;                                        // 2 MB
  float*  t_part = s_part + (size_t)JBLK * MM;                      // 2 MB
  float*  P_part = t_part + (size_t)JBLK * MM;                      // 16 KB
  double* acc    = (double*)(P_part + JBLK * JBLK);                 // 32 B

  hipMemsetAsync(acc, 0, 4 * sizeof(double), stream);

  convert_kernel<<<MM / 4, 256, 0, stream>>>(x, y, xb, yb, sqx, sqy);

  dim3 grid(MM / 128, MM / 128);
  hsic_pair_kernel<<<grid, 256, 0, stream>>>(xb, yb, sqx, sqy, s_part, t_part, P_part);

  reduce1_kernel<<<JBLK, 128, 0, stream>>>(s_part, t_part, P_part, acc);
  reduce2_kernel<<<1, 1, 0, stream>>>(acc, (float*)d_out);
}

// Round 5
// 111.192 us; speedup vs baseline: 2.1818x; 2.1818x over previous
//
#include <hip/hip_runtime.h>
#include <hip/hip_bf16.h>

typedef unsigned short u16;
typedef unsigned int   u32;

#define MM 8192
#define DD 128
#define JBLK 64            // MM/128 column blocks

using short8 = __attribute__((ext_vector_type(8))) short;
using f32x4  = __attribute__((ext_vector_type(4))) float;

__device__ __forceinline__ u16 f2bf(float f) {
  u32 u = __float_as_uint(f);
  u32 r = u + 0x7fffu + ((u >> 16) & 1u);   // RNE
  return (u16)(r >> 16);
}

#define GLOAD_LDS16(g, l)                                          \
  __builtin_amdgcn_global_load_lds(                                \
      (const __attribute__((address_space(1))) void*)(g),          \
      (__attribute__((address_space(3))) void*)(l), 16, 0, 0)

// One wave per row: bf16 conversion + squared norms.
__global__ __launch_bounds__(256) void convert_kernel(
    const float* __restrict__ x, const float* __restrict__ y,
    u16* __restrict__ xb, u16* __restrict__ yb,
    float* __restrict__ sqx, float* __restrict__ sqy)
{
  const int wid  = threadIdx.x >> 6;
  const int lane = threadIdx.x & 63;
  const int row  = blockIdx.x * 4 + wid;
  const float2 vx = *(const float2*)(x + (size_t)row * DD + lane * 2);
  const float2 vy = *(const float2*)(y + (size_t)row * DD + lane * 2);
  float sx = vx.x * vx.x + vx.y * vx.y;
  float sy = vy.x * vy.x + vy.y * vy.y;
  #pragma unroll
  for (int off = 1; off < 64; off <<= 1) {
    sx += __shfl_xor(sx, off, 64);
    sy += __shfl_xor(sy, off, 64);
  }
  u32 px = (u32)f2bf(vx.x) | ((u32)f2bf(vx.y) << 16);
  u32 py = (u32)f2bf(vy.x) | ((u32)f2bf(vy.y) << 16);
  *(u32*)(xb + (size_t)row * DD + lane * 2) = px;
  *(u32*)(yb + (size_t)row * DD + lane * 2) = py;
  if (lane == 0) { sqx[row] = sx; sqy[row] = sy; }
}

// 128x128 tile / block, 4 waves 2x2, wave = 64x64.
// Tiles staged in LDS via global_load_lds(16B) with source-side XOR swizzle
// (chunk ^= row&7) so ds_read_b128 fragment reads are ~2-way conflict (free).
// X phase then Y phase reuse the same 64KB LDS. No device atomics.
__global__ __launch_bounds__(256, 2) void hsic_pair_kernel(
    const u16* __restrict__ xb, const u16* __restrict__ yb,
    const float* __restrict__ sqx, const float* __restrict__ sqy,
    float* __restrict__ s_part, float* __restrict__ t_part,
    float* __restrict__ P_part)
{
  const int i0   = blockIdx.y * 128;
  const int j0   = blockIdx.x * 128;
  const int tid  = threadIdx.x;
  const int wid  = tid >> 6;
  const int lane = tid & 63;
  const int wr   = wid >> 1;
  const int wc   = wid & 1;
  const int g    = lane >> 4;   // 0..3
  const int c    = lane & 15;   // 0..15

  const int ri = i0 + wr * 64;
  const int cj = j0 + wc * 64;

  __shared__ u16 lA[128 * 128];   // 32 KB (swizzled storage)
  __shared__ u16 lB[128 * 128];   // 32 KB
  __shared__ float lds_s[128];
  __shared__ float lds_t[128];
  __shared__ float red[4];
  if (tid < 128) { lds_s[tid] = 0.f; lds_t[tid] = 0.f; }

  // Per-thread staging geometry: 8 x 16B chunks per tile per thread.
  // LDS dest (linear, wave-uniform base + lane*16): o = i*4096 + tid*16.
  // Source (pre-swizzled): row r = o>>8, chunk c16 = (o>>4)&15,
  //   src = (r<<8) | ((c16 ^ (r&7))<<4).
  int so_[8], do_[8];
  #pragma unroll
  for (int i = 0; i < 8; ++i) {
    const int o   = i * 4096 + tid * 16;
    const int r   = o >> 8;
    const int c16 = (o >> 4) & 15;
    so_[i] = (r << 8) | ((c16 ^ (r & 7)) << 4);
    do_[i] = i * 4096 + wid * 1024;       // lane-invariant base
  }

  const char* gAx = (const char*)xb + (size_t)i0 * 256;
  const char* gBx = (const char*)xb + (size_t)j0 * 256;

  // ---- stage X tiles ----
  #pragma unroll
  for (int i = 0; i < 8; ++i) {
    GLOAD_LDS16(gAx + so_[i], (char*)lA + do_[i]);
    GLOAD_LDS16(gBx + so_[i], (char*)lB + do_[i]);
  }
  __syncthreads();   // drains vmcnt (global_load_lds) + barrier

  f32x4 accX[4][4];
  f32x4 accY[4][4];
  #pragma unroll
  for (int rs = 0; rs < 4; ++rs)
    #pragma unroll
    for (int cs = 0; cs < 4; ++cs) {
      accX[rs][cs] = (f32x4){0.f, 0.f, 0.f, 0.f};
      accY[rs][cs] = (f32x4){0.f, 0.f, 0.f, 0.f};
    }

  // Fragment read: element offset = row*128 + (chunk ^ (row&7))*8.
  #define FRAG(Larr, row, ch) \
    (*(const short8*)((Larr) + (((row) << 7) + (((ch) ^ ((row) & 7)) << 3))))

  // ---- X phase ----
  #pragma unroll
  for (int kk = 0; kk < 4; ++kk) {
    short8 b[4], a[4];
    #pragma unroll
    for (int cs = 0; cs < 4; ++cs) b[cs] = FRAG(lB, wc * 64 + cs * 16 + c, kk * 4 + g);
    #pragma unroll
    for (int rs = 0; rs < 4; ++rs) a[rs] = FRAG(lA, wr * 64 + rs * 16 + c, kk * 4 + g);
    #pragma unroll
    for (int rs = 0; rs < 4; ++rs)
      #pragma unroll
      for (int cs = 0; cs < 4; ++cs)
        accX[rs][cs] = __builtin_amdgcn_mfma_f32_16x16x32_bf16(a[rs], b[cs], accX[rs][cs], 0, 0, 0);
  }
  __syncthreads();   // all X reads done before overwriting LDS

  // ---- stage Y tiles (same LDS) ----
  const char* gAy = (const char*)yb + (size_t)i0 * 256;
  const char* gBy = (const char*)yb + (size_t)j0 * 256;
  #pragma unroll
  for (int i = 0; i < 8; ++i) {
    GLOAD_LDS16(gAy + so_[i], (char*)lA + do_[i]);
    GLOAD_LDS16(gBy + so_[i], (char*)lB + do_[i]);
  }
  __syncthreads();

  // ---- Y phase ----
  #pragma unroll
  for (int kk = 0; kk < 4; ++kk) {
    short8 b[4], a[4];
    #pragma unroll
    for (int cs = 0; cs < 4; ++cs) b[cs] = FRAG(lB, wc * 64 + cs * 16 + c, kk * 4 + g);
    #pragma unroll
    for (int rs = 0; rs < 4; ++rs) a[rs] = FRAG(lA, wr * 64 + rs * 16 + c, kk * 4 + g);
    #pragma unroll
    for (int rs = 0; rs < 4; ++rs)
      #pragma unroll
      for (int cs = 0; cs < 4; ++cs)
        accY[rs][cs] = __builtin_amdgcn_mfma_f32_16x16x32_bf16(a[rs], b[cs], accY[rs][cs], 0, 0, 0);
  }

  // ---- epilogue ----
  float sqxc[4], sqyc[4];
  #pragma unroll
  for (int cs = 0; cs < 4; ++cs) {
    sqxc[cs] = sqx[cj + cs * 16 + c];
    sqyc[cs] = sqy[cj + cs * 16 + c];
  }

  float p_acc = 0.f;

  #pragma unroll
  for (int rs = 0; rs < 4; ++rs) {
    const f32x4 sxr = *(const f32x4*)(sqx + ri + rs * 16 + g * 4);
    const f32x4 syr = *(const f32x4*)(sqy + ri + rs * 16 + g * 4);

    float s_acc[4] = {0.f, 0.f, 0.f, 0.f};
    float t_acc[4] = {0.f, 0.f, 0.f, 0.f};

    #pragma unroll
    for (int cs = 0; cs < 4; ++cs) {
      const int gc = cj + cs * 16 + c;
      #pragma unroll
      for (int tt = 0; tt < 4; ++tt) {
        const int gr = ri + rs * 16 + g * 4 + tt;
        float kx, ly;
        if (gr == gc) {
          kx = 1.f; ly = 1.f;   // exact diagonal (off-diagonals underflow anyway)
        } else {
          kx = __expf(2.f * accX[rs][cs][tt] - sxr[tt] - sqxc[cs]);
          ly = __expf(2.f * accY[rs][cs][tt] - syr[tt] - sqyc[cs]);
        }
        p_acc     += kx * ly;
        s_acc[tt] += kx;
        t_acc[tt] += ly;
      }
    }

    #pragma unroll
    for (int tt = 0; tt < 4; ++tt) {
      float sv = s_acc[tt];
      float tv = t_acc[tt];
      #pragma unroll
      for (int off = 1; off < 16; off <<= 1) {
        sv += __shfl_xor(sv, off, 64);
        tv += __shfl_xor(tv, off, 64);
      }
      if (c == 0) {
        const int lrow = wr * 64 + rs * 16 + g * 4 + tt;
        atomicAdd(&lds_s[lrow], sv);   // LDS atomic (lgkm, cheap)
        atomicAdd(&lds_t[lrow], tv);
      }
    }
  }

  // Block-reduce P.
  #pragma unroll
  for (int off = 1; off < 64; off <<= 1) p_acc += __shfl_xor(p_acc, off, 64);
  if (lane == 0) red[wid] = p_acc;
  __syncthreads();

  // Plain coalesced stores of per-block partials (no device atomics).
  if (tid < 128) {
    s_part[(size_t)blockIdx.x * MM + i0 + tid] = lds_s[tid];
    t_part[(size_t)blockIdx.x * MM + i0 + tid] = lds_t[tid];
  }
  if (tid == 0)
    P_part[blockIdx.y * gridDim.x + blockIdx.x] = red[0] + red[1] + red[2] + red[3];
}

// 64 blocks x 128 threads: fold column-block partials, produce the 4 scalars.
__global__ __launch_bounds__(128) void reduce1_kernel(
    const float* __restrict__ s_part, const float* __restrict__ t_part,
    const float* __restrict__ P_part, double* __restrict__ acc)
{
  const int tid = threadIdx.x;
  const int row = blockIdx.x * 128 + tid;
  float sv = 0.f, tv = 0.f;
  for (int jb = 0; jb < JBLK; ++jb) {
    sv += s_part[(size_t)jb * MM + row];
    tv += t_part[(size_t)jb * MM + row];
  }
  float cv = sv * tv;
  float pv = (tid < 64) ? P_part[blockIdx.x * 64 + tid] : 0.f;
  #pragma unroll
  for (int off = 1; off < 64; off <<= 1) {
    sv += __shfl_xor(sv, off, 64);
    tv += __shfl_xor(tv, off, 64);
    cv += __shfl_xor(cv, off, 64);
    pv += __shfl_xor(pv, off, 64);
  }
  __shared__ float r[2][4];
  const int w = tid >> 6;
  if ((tid & 63) == 0) { r[w][0] = sv; r[w][1] = tv; r[w][2] = cv; r[w][3] = pv; }
  __syncthreads();
  if (tid == 0) {
    atomicAdd(&acc[0], (double)(r[0][0] + r[1][0]));
    atomicAdd(&acc[1], (double)(r[0][1] + r[1][1]));
    atomicAdd(&acc[2], (double)(r[0][2] + r[1][2]));
    atomicAdd(&acc[3], (double)(r[0][3] + r[1][3]));
  }
}

__global__ void reduce2_kernel(const double* __restrict__ acc,
                               float* __restrict__ out)
{
  const double m   = (double)MM;
  const double num = acc[3] - (2.0 / m) * acc[2] + (acc[0] * acc[1]) / (m * m);
  out[0] = (float)(num / ((m - 1.0) * (m - 1.0)));
}

extern "C" void kernel_launch(void* const* d_in, const int* in_sizes, int n_in,
                              void* d_out, int out_size, void* d_ws, size_t ws_size,
                              hipStream_t stream) {
  const float* x = (const float*)d_in[0];
  const float* y = (const float*)d_in[1];

  char* ws = (char*)d_ws;
  u16*    xb     = (u16*)ws;                                        // 2 MB
  u16*    yb     = (u16*)(ws + (size_t)2 * 1024 * 1024);            // 2 MB
  float*  sqx    = (float*)(ws + (size_t)4 * 1024 * 1024);          // 32 KB
  float*  sqy    = sqx + MM;                                        // 32 KB
  float*  s_part = sqy + MM;                                        // 2 MB
  float*  t_part = s_part + (size_t)JBLK * MM;                      // 2 MB
  float*  P_part = t_part + (size_t)JBLK * MM;                      // 16 KB
  double* acc    = (double*)(P_part + JBLK * JBLK);                 // 32 B

  hipMemsetAsync(acc, 0, 4 * sizeof(double), stream);

  convert_kernel<<<MM / 4, 256, 0, stream>>>(x, y, xb, yb, sqx, sqy);

  dim3 grid(MM / 128, MM / 128);
  hsic_pair_kernel<<<grid, 256, 0, stream>>>(xb, yb, sqx, sqy, s_part, t_part, P_part);

  reduce1_kernel<<<JBLK, 128, 0, stream>>>(s_part, t_part, P_part, acc);
  reduce2_kernel<<<1, 1, 0, stream>>>(acc, (float*)d_out);
}

// Round 6
// 82.776 us; speedup vs baseline: 2.9307x; 1.3433x over previous
//
#include <hip/hip_runtime.h>
#include <hip/hip_bf16.h>

typedef unsigned short u16;
typedef unsigned int   u32;

#define MM 8192
#define DD 128
#define NB 64                    // 128-row bands
#define NTRI (NB * (NB + 1) / 2) // 2080 upper-triangle blocks
#define SKIP_THR -40.0f

using short8 = __attribute__((ext_vector_type(8))) short;
using f32x4  = __attribute__((ext_vector_type(4))) float;

__device__ __forceinline__ u16 f2bf(float f) {
  u32 u = __float_as_uint(f);
  u32 r = u + 0x7fffu + ((u >> 16) & 1u);   // RNE
  return (u16)(r >> 16);
}

#define GLOAD_LDS16(g, l)                                          \
  __builtin_amdgcn_global_load_lds(                                \
      (const __attribute__((address_space(1))) void*)(g),          \
      (__attribute__((address_space(3))) void*)(l), 16, 0, 0)

// One wave per row: bf16 conversion + squared norms.
__global__ __launch_bounds__(256) void convert_kernel(
    const float* __restrict__ x, const float* __restrict__ y,
    u16* __restrict__ xb, u16* __restrict__ yb,
    float* __restrict__ sqx, float* __restrict__ sqy)
{
  const int wid  = threadIdx.x >> 6;
  const int lane = threadIdx.x & 63;
  const int row  = blockIdx.x * 4 + wid;
  const float2 vx = *(const float2*)(x + (size_t)row * DD + lane * 2);
  const float2 vy = *(const float2*)(y + (size_t)row * DD + lane * 2);
  float sx = vx.x * vx.x + vx.y * vx.y;
  float sy = vy.x * vy.x + vy.y * vy.y;
  #pragma unroll
  for (int off = 1; off < 64; off <<= 1) {
    sx += __shfl_xor(sx, off, 64);
    sy += __shfl_xor(sy, off, 64);
  }
  u32 px = (u32)f2bf(vx.x) | ((u32)f2bf(vx.y) << 16);
  u32 py = (u32)f2bf(vy.x) | ((u32)f2bf(vy.y) << 16);
  *(u32*)(xb + (size_t)row * DD + lane * 2) = px;
  *(u32*)(yb + (size_t)row * DD + lane * 2) = py;
  if (lane == 0) { sqx[row] = sx; sqy[row] = sy; }
}

// Upper-triangle 128x128 blocks (ib <= jb), 4 waves 2x2, wave = 64x64.
// LDS staging with source-side XOR swizzle; X phase then Y phase reuse the
// same 64KB. Epilogue: per-subtile underflow skip-vote; row sums (band ib)
// and column sums (band jb, = transpose row sums by symmetry) to LDS, then
// plain per-block stores. P weighted x2 for off-diagonal blocks.
__global__ __launch_bounds__(256, 2) void hsic_pair_kernel(
    const u16* __restrict__ xb, const u16* __restrict__ yb,
    const float* __restrict__ sqx, const float* __restrict__ sqy,
    float* __restrict__ part_s, float* __restrict__ part_t,
    float* __restrict__ P_part)
{
  const int bid = blockIdx.x;
  // bid -> (ib, jb), ib <= jb, row-major over shrinking rows.
  int ib = (int)(64.5f - sqrtf(64.5f * 64.5f - 2.0f * (float)bid));
  if (ib > NB - 1) ib = NB - 1;
  if (ib < 0) ib = 0;
  while (ib > 0 && (ib * NB - ib * (ib - 1) / 2) > bid) --ib;
  while (ib < NB - 1 && ((ib + 1) * NB - (ib + 1) * ib / 2) <= bid) ++ib;
  const int jb = ib + (bid - (ib * NB - ib * (ib - 1) / 2));

  const int i0   = ib * 128;
  const int j0   = jb * 128;
  const int tid  = threadIdx.x;
  const int wid  = tid >> 6;
  const int lane = tid & 63;
  const int wr   = wid >> 1;
  const int wc   = wid & 1;
  const int g    = lane >> 4;   // 0..3
  const int c    = lane & 15;   // 0..15

  const int ri = i0 + wr * 64;
  const int cj = j0 + wc * 64;

  __shared__ u16 lA[128 * 128];   // 32 KB (swizzled storage)
  __shared__ u16 lB[128 * 128];   // 32 KB
  __shared__ float lds_sr[128], lds_sc[128], lds_tr[128], lds_tc[128];
  __shared__ float red[4];
  if (tid < 128) {
    lds_sr[tid] = 0.f; lds_sc[tid] = 0.f;
    lds_tr[tid] = 0.f; lds_tc[tid] = 0.f;
  }

  // Staging geometry: LDS dest linear (wave-uniform base + lane*16);
  // source pre-swizzled: chunk ^= row&7 (16B granularity).
  int so_[8], do_[8];
  #pragma unroll
  for (int i = 0; i < 8; ++i) {
    const int o   = i * 4096 + tid * 16;
    const int r   = o >> 8;
    const int c16 = (o >> 4) & 15;
    so_[i] = (r << 8) | ((c16 ^ (r & 7)) << 4);
    do_[i] = i * 4096 + wid * 1024;       // lane-invariant base
  }

  const char* gAx = (const char*)xb + (size_t)i0 * 256;
  const char* gBx = (const char*)xb + (size_t)j0 * 256;

  // ---- stage X tiles ----
  #pragma unroll
  for (int i = 0; i < 8; ++i) {
    GLOAD_LDS16(gAx + so_[i], (char*)lA + do_[i]);
    GLOAD_LDS16(gBx + so_[i], (char*)lB + do_[i]);
  }
  __syncthreads();

  f32x4 accX[4][4];
  f32x4 accY[4][4];
  #pragma unroll
  for (int rs = 0; rs < 4; ++rs)
    #pragma unroll
    for (int cs = 0; cs < 4; ++cs) {
      accX[rs][cs] = (f32x4){0.f, 0.f, 0.f, 0.f};
      accY[rs][cs] = (f32x4){0.f, 0.f, 0.f, 0.f};
    }

  // Fragment read: element offset = row*128 + (chunk ^ (row&7))*8.
  #define FRAG(Larr, row, ch) \
    (*(const short8*)((Larr) + (((row) << 7) + (((ch) ^ ((row) & 7)) << 3))))

  // ---- X phase ----
  #pragma unroll
  for (int kk = 0; kk < 4; ++kk) {
    short8 b[4], a[4];
    #pragma unroll
    for (int cs = 0; cs < 4; ++cs) b[cs] = FRAG(lB, wc * 64 + cs * 16 + c, kk * 4 + g);
    #pragma unroll
    for (int rs = 0; rs < 4; ++rs) a[rs] = FRAG(lA, wr * 64 + rs * 16 + c, kk * 4 + g);
    #pragma unroll
    for (int rs = 0; rs < 4; ++rs)
      #pragma unroll
      for (int cs = 0; cs < 4; ++cs)
        accX[rs][cs] = __builtin_amdgcn_mfma_f32_16x16x32_bf16(a[rs], b[cs], accX[rs][cs], 0, 0, 0);
  }
  __syncthreads();   // all X reads done before overwriting LDS

  // ---- stage Y tiles (same LDS) ----
  const char* gAy = (const char*)yb + (size_t)i0 * 256;
  const char* gBy = (const char*)yb + (size_t)j0 * 256;
  #pragma unroll
  for (int i = 0; i < 8; ++i) {
    GLOAD_LDS16(gAy + so_[i], (char*)lA + do_[i]);
    GLOAD_LDS16(gBy + so_[i], (char*)lB + do_[i]);
  }
  __syncthreads();

  // ---- Y phase ----
  #pragma unroll
  for (int kk = 0; kk < 4; ++kk) {
    short8 b[4], a[4];
    #pragma unroll
    for (int cs = 0; cs < 4; ++cs) b[cs] = FRAG(lB, wc * 64 + cs * 16 + c, kk * 4 + g);
    #pragma unroll
    for (int rs = 0; rs < 4; ++rs) a[rs] = FRAG(lA, wr * 64 + rs * 16 + c, kk * 4 + g);
    #pragma unroll
    for (int rs = 0; rs < 4; ++rs)
      #pragma unroll
      for (int cs = 0; cs < 4; ++cs)
        accY[rs][cs] = __builtin_amdgcn_mfma_f32_16x16x32_bf16(a[rs], b[cs], accY[rs][cs], 0, 0, 0);
  }

  // ---- epilogue ----
  float sqxc[4], sqyc[4];
  #pragma unroll
  for (int cs = 0; cs < 4; ++cs) {
    sqxc[cs] = sqx[cj + cs * 16 + c];
    sqyc[cs] = sqy[cj + cs * 16 + c];
  }

  float p_acc = 0.f;
  float scol_acc[4] = {0.f, 0.f, 0.f, 0.f};   // per cs, band jb columns
  float tcol_acc[4] = {0.f, 0.f, 0.f, 0.f};

  #pragma unroll
  for (int rs = 0; rs < 4; ++rs) {
    const f32x4 sxr = *(const f32x4*)(sqx + ri + rs * 16 + g * 4);
    const f32x4 syr = *(const f32x4*)(sqy + ri + rs * 16 + g * 4);

    float sr_acc[4] = {0.f, 0.f, 0.f, 0.f};
    float tr_acc[4] = {0.f, 0.f, 0.f, 0.f};
    bool rowx = false, rowy = false;

    #pragma unroll
    for (int cs = 0; cs < 4; ++cs) {
      float ex[4], ey[4];
      #pragma unroll
      for (int tt = 0; tt < 4; ++tt) {
        ex[tt] = 2.f * accX[rs][cs][tt] - sxr[tt] - sqxc[cs];
        ey[tt] = 2.f * accY[rs][cs][tt] - syr[tt] - sqyc[cs];
      }
      const float mxx = fmaxf(fmaxf(ex[0], ex[1]), fmaxf(ex[2], ex[3]));
      const float mxy = fmaxf(fmaxf(ey[0], ey[1]), fmaxf(ey[2], ey[3]));
      const bool skipx = __all(mxx < SKIP_THR);
      const bool skipy = __all(mxy < SKIP_THR);
      if (skipx && skipy) continue;   // wave-uniform

      const int gc = cj + cs * 16 + c;
      float kx[4], ly[4];
      #pragma unroll
      for (int tt = 0; tt < 4; ++tt) {
        const int gr = ri + rs * 16 + g * 4 + tt;
        kx[tt] = skipx ? 0.f : ((gr == gc) ? 1.f : __expf(ex[tt]));
        ly[tt] = skipy ? 0.f : ((gr == gc) ? 1.f : __expf(ey[tt]));
      }
      if (!skipx) {
        rowx = true;
        float sc_ = 0.f;
        #pragma unroll
        for (int tt = 0; tt < 4; ++tt) { sr_acc[tt] += kx[tt]; sc_ += kx[tt]; }
        sc_ += __shfl_xor(sc_, 16, 64);   // reduce over g-lanes (16 rows of subtile)
        sc_ += __shfl_xor(sc_, 32, 64);
        scol_acc[cs] += sc_;
      }
      if (!skipy) {
        rowy = true;
        float tc_ = 0.f;
        #pragma unroll
        for (int tt = 0; tt < 4; ++tt) { tr_acc[tt] += ly[tt]; tc_ += ly[tt]; }
        tc_ += __shfl_xor(tc_, 16, 64);
        tc_ += __shfl_xor(tc_, 32, 64);
        tcol_acc[cs] += tc_;
      }
      if (!skipx && !skipy) {
        #pragma unroll
        for (int tt = 0; tt < 4; ++tt) p_acc += kx[tt] * ly[tt];
      }
    }

    // Row-sum reduce across the 16 c-lanes; accumulate LDS (band ib rows).
    if (rowx) {
      #pragma unroll
      for (int tt = 0; tt < 4; ++tt) {
        float sv = sr_acc[tt];
        #pragma unroll
        for (int off = 1; off < 16; off <<= 1) sv += __shfl_xor(sv, off, 64);
        if (c == 0) atomicAdd(&lds_sr[wr * 64 + rs * 16 + g * 4 + tt], sv);
      }
    }
    if (rowy) {
      #pragma unroll
      for (int tt = 0; tt < 4; ++tt) {
        float tv = tr_acc[tt];
        #pragma unroll
        for (int off = 1; off < 16; off <<= 1) tv += __shfl_xor(tv, off, 64);
        if (c == 0) atomicAdd(&lds_tr[wr * 64 + rs * 16 + g * 4 + tt], tv);
      }
    }
  }

  // Column sums (band jb rows via symmetry): one LDS add per (cs, c).
  if (g == 0) {
    #pragma unroll
    for (int cs = 0; cs < 4; ++cs) {
      atomicAdd(&lds_sc[wc * 64 + cs * 16 + c], scol_acc[cs]);
      atomicAdd(&lds_tc[wc * 64 + cs * 16 + c], tcol_acc[cs]);
    }
  }

  // Block-reduce P.
  #pragma unroll
  for (int off = 1; off < 64; off <<= 1) p_acc += __shfl_xor(p_acc, off, 64);
  if (lane == 0) red[wid] = p_acc;
  __syncthreads();

  // Plain per-block stores (no device atomics).
  if (tid < 128) {
    part_s[(size_t)bid * 256 + tid]       = lds_sr[tid];
    part_s[(size_t)bid * 256 + 128 + tid] = lds_sc[tid];
    part_t[(size_t)bid * 256 + tid]       = lds_tr[tid];
    part_t[(size_t)bid * 256 + 128 + tid] = lds_tc[tid];
  }
  if (tid == 0) {
    const float w = (ib == jb) ? 1.f : 2.f;
    P_part[bid] = w * (red[0] + red[1] + red[2] + red[3]);
  }
}

// 64 blocks (one per band) x 128 threads: assemble full row sums from
// row-parts (blocks (b, jb>=b)) and col-parts (blocks (ib<b, b)).
__global__ __launch_bounds__(128) void reduce1_kernel(
    const float* __restrict__ part_s, const float* __restrict__ part_t,
    const float* __restrict__ P_part, double* __restrict__ acc)
{
  const int b   = blockIdx.x;
  const int tid = threadIdx.x;

  float sv = 0.f, tv = 0.f;
  const int base = b * NB - b * (b - 1) / 2;         // bid of (b, b)
  for (int k = 0; k < NB - b; ++k) {                 // row parts (b, b+k)
    sv += part_s[(size_t)(base + k) * 256 + tid];
    tv += part_t[(size_t)(base + k) * 256 + tid];
  }
  for (int ibb = 0; ibb < b; ++ibb) {                // col parts (ibb, b)
    const int bb = ibb * NB - ibb * (ibb - 1) / 2 + (b - ibb);
    sv += part_s[(size_t)bb * 256 + 128 + tid];
    tv += part_t[(size_t)bb * 256 + 128 + tid];
  }
  float cv = sv * tv;

  float pv = 0.f;                                    // P chunk [b*33, b*33+33)
  for (int i = b * 33 + tid; i < (b * 33 + 33 < NTRI ? b * 33 + 33 : NTRI); i += 128)
    pv += P_part[i];

  #pragma unroll
  for (int off = 1; off < 64; off <<= 1) {
    sv += __shfl_xor(sv, off, 64);
    tv += __shfl_xor(tv, off, 64);
    cv += __shfl_xor(cv, off, 64);
    pv += __shfl_xor(pv, off, 64);
  }
  __shared__ float r[2][4];
  const int w = tid >> 6;
  if ((tid & 63) == 0) { r[w][0] = sv; r[w][1] = tv; r[w][2] = cv; r[w][3] = pv; }
  __syncthreads();
  if (tid == 0) {
    atomicAdd(&acc[0], (double)(r[0][0] + r[1][0]));
    atomicAdd(&acc[1], (double)(r[0][1] + r[1][1]));
    atomicAdd(&acc[2], (double)(r[0][2] + r[1][2]));
    atomicAdd(&acc[3], (double)(r[0][3] + r[1][3]));
  }
}

__global__ void reduce2_kernel(const double* __restrict__ acc,
                               float* __restrict__ out)
{
  const double m   = (double)MM;
  const double num = acc[3] - (2.0 / m) * acc[2] + (acc[0] * acc[1]) / (m * m);
  out[0] = (float)(num / ((m - 1.0) * (m - 1.0)));
}

extern "C" void kernel_launch(void* const* d_in, const int* in_sizes, int n_in,
                              void* d_out, int out_size, void* d_ws, size_t ws_size,
                              hipStream_t stream) {
  const float* x = (const float*)d_in[0];
  const float* y = (const float*)d_in[1];

  char* ws = (char*)d_ws;
  u16*    xb     = (u16*)ws;                                        // 2 MB
  u16*    yb     = (u16*)(ws + (size_t)2 * 1024 * 1024);            // 2 MB
  float*  sqx    = (float*)(ws + (size_t)4 * 1024 * 1024);          // 32 KB
  float*  sqy    = sqx + MM;                                        // 32 KB
  float*  part_s = sqy + MM;                                        // 2.13 MB
  float*  part_t = part_s + (size_t)NTRI * 256;                     // 2.13 MB
  float*  P_part = part_t + (size_t)NTRI * 256;                     // 8.3 KB
  double* acc    = (double*)(P_part + NTRI);                        // 32 B

  hipMemsetAsync(acc, 0, 4 * sizeof(double), stream);

  convert_kernel<<<MM / 4, 256, 0, stream>>>(x, y, xb, yb, sqx, sqy);

  hsic_pair_kernel<<<NTRI, 256, 0, stream>>>(xb, yb, sqx, sqy, part_s, part_t, P_part);

  reduce1_kernel<<<NB, 128, 0, stream>>>(part_s, part_t, P_part, acc);
  reduce2_kernel<<<1, 1, 0, stream>>>(acc, (float*)d_out);
}

// Round 7
// 61.103 us; speedup vs baseline: 3.9702x; 1.3547x over previous
//
#include <hip/hip_runtime.h>
#include <hip/hip_bf16.h>

typedef unsigned short u16;
typedef unsigned int   u32;

#define MM 8192
#define DD 128
#define NB 64                    // 128-row bands
#define NTRI (NB * (NB + 1) / 2) // 2080 upper-triangle blocks
#define SKIP_THR -40.0f

using short8 = __attribute__((ext_vector_type(8))) short;
using f32x4  = __attribute__((ext_vector_type(4))) float;

__device__ __forceinline__ u16 f2bf(float f) {
  u32 u = __float_as_uint(f);
  u32 r = u + 0x7fffu + ((u >> 16) & 1u);   // RNE
  return (u16)(r >> 16);
}

#define GLOAD_LDS16(g, l)                                          \
  __builtin_amdgcn_global_load_lds(                                \
      (const __attribute__((address_space(1))) void*)(g),          \
      (__attribute__((address_space(3))) void*)(l), 16, 0, 0)

// One wave per 2 rows (float4 loads): bf16 conversion + squared norms.
__global__ __launch_bounds__(256) void convert_kernel(
    const float* __restrict__ x, const float* __restrict__ y,
    u16* __restrict__ xb, u16* __restrict__ yb,
    float* __restrict__ sqx, float* __restrict__ sqy)
{
  const int wid  = threadIdx.x >> 6;
  const int lane = threadIdx.x & 63;
  const int l32  = lane & 31;
  const int row  = blockIdx.x * 8 + wid * 2 + (lane >> 5);
  const float4 vx = *(const float4*)(x + (size_t)row * DD + l32 * 4);
  const float4 vy = *(const float4*)(y + (size_t)row * DD + l32 * 4);
  float sx = vx.x * vx.x + vx.y * vx.y + vx.z * vx.z + vx.w * vx.w;
  float sy = vy.x * vy.x + vy.y * vy.y + vy.z * vy.z + vy.w * vy.w;
  #pragma unroll
  for (int off = 1; off < 32; off <<= 1) {   // stays within 32-lane half
    sx += __shfl_xor(sx, off, 64);
    sy += __shfl_xor(sy, off, 64);
  }
  uint2 px, py;
  px.x = (u32)f2bf(vx.x) | ((u32)f2bf(vx.y) << 16);
  px.y = (u32)f2bf(vx.z) | ((u32)f2bf(vx.w) << 16);
  py.x = (u32)f2bf(vy.x) | ((u32)f2bf(vy.y) << 16);
  py.y = (u32)f2bf(vy.z) | ((u32)f2bf(vy.w) << 16);
  *(uint2*)(xb + (size_t)row * DD + l32 * 4) = px;
  *(uint2*)(yb + (size_t)row * DD + l32 * 4) = py;
  if (l32 == 0) { sqx[row] = sx; sqy[row] = sy; }
}

// Upper-triangle 128x128 blocks (ib <= jb), 4 waves 2x2, wave = 64x64.
// Double-buffered BK=64 staging: rounds X-K0, X-K1, Y-K0, Y-K1 alternate two
// 32KB LDS buffers; stage(r+1) issued BEFORE compute(r) so the L2 flight
// overlaps ds_read+MFMA. Source-side XOR swizzle keeps ds_read_b128 ~2-way.
// Epilogue: per-subtile underflow skip-vote; row/col sums -> LDS -> plain
// per-block stores into band-keyed comb[][] layout. No device atomics.
__global__ __launch_bounds__(256, 2) void hsic_pair_kernel(
    const u16* __restrict__ xb, const u16* __restrict__ yb,
    const float* __restrict__ sqx, const float* __restrict__ sqy,
    float* __restrict__ comb_s, float* __restrict__ comb_t,
    float* __restrict__ P_part)
{
  const int bid = blockIdx.x;
  // bid -> (ib, jb), ib <= jb, row-major over shrinking rows.
  int ib = (int)(64.5f - sqrtf(64.5f * 64.5f - 2.0f * (float)bid));
  if (ib > NB - 1) ib = NB - 1;
  if (ib < 0) ib = 0;
  while (ib > 0 && (ib * NB - ib * (ib - 1) / 2) > bid) --ib;
  while (ib < NB - 1 && ((ib + 1) * NB - (ib + 1) * ib / 2) <= bid) ++ib;
  const int jb = ib + (bid - (ib * NB - ib * (ib - 1) / 2));

  const int i0   = ib * 128;
  const int j0   = jb * 128;
  const int tid  = threadIdx.x;
  const int wid  = tid >> 6;
  const int lane = tid & 63;
  const int wr   = wid >> 1;
  const int wc   = wid & 1;
  const int g    = lane >> 4;   // 0..3
  const int c    = lane & 15;   // 0..15

  const int ri = i0 + wr * 64;
  const int cj = j0 + wc * 64;

  __shared__ u16 lT[2][2][128 * 64];   // [buf][A/B][rows x BK] = 64 KB
  __shared__ float lds_sr[128], lds_sc[128], lds_tr[128], lds_tc[128];
  __shared__ float red[4];
  if (tid < 128) {
    lds_sr[tid] = 0.f; lds_sc[tid] = 0.f;
    lds_tr[tid] = 0.f; lds_tc[tid] = 0.f;
  }

  // Staging geometry (per 16KB half-tile): 4 x 16B chunks per thread.
  // LDS dest linear: o = i*4096 + tid*16 (base excludes lane*16).
  // Source pre-swizzled: row r = o>>7, chunk ch = (o>>4)&7,
  //   src byte = r*256 + (ch ^ (r&7))*16   (+ kh*128 per round).
  int so_[4];
  #pragma unroll
  for (int i = 0; i < 4; ++i) {
    const int o  = i * 4096 + tid * 16;
    const int r  = o >> 7;
    const int ch = (o >> 4) & 7;
    so_[i] = r * 256 + ((ch ^ (r & 7)) << 4);
  }

  const char* gAx = (const char*)xb + (size_t)i0 * 256;
  const char* gBx = (const char*)xb + (size_t)j0 * 256;
  const char* gAy = (const char*)yb + (size_t)i0 * 256;
  const char* gBy = (const char*)yb + (size_t)j0 * 256;

#define STAGE(R) do {                                                   \
    const char* gA_ = (((R) >> 1) ? gAy : gAx) + ((R) & 1) * 128;       \
    const char* gB_ = (((R) >> 1) ? gBy : gBx) + ((R) & 1) * 128;       \
    char* dA_ = (char*)&lT[(R) & 1][0][0] + wid * 1024;                 \
    char* dB_ = (char*)&lT[(R) & 1][1][0] + wid * 1024;                 \
    _Pragma("unroll") for (int i = 0; i < 4; ++i) {                     \
      GLOAD_LDS16(gA_ + so_[i], dA_ + i * 4096);                        \
      GLOAD_LDS16(gB_ + so_[i], dB_ + i * 4096);                        \
    }                                                                   \
  } while (0)

  // Fragment read in a 16KB half-tile: elem = row*64 + (ch ^ (row&7))*8.
#define FRAG2(Lp, row, ch) \
  (*(const short8*)((Lp) + (((row) << 6) + (((ch) ^ ((row) & 7)) << 3))))

#define COMPUTE(ACC, BUF) do {                                          \
    _Pragma("unroll") for (int kk2 = 0; kk2 < 2; ++kk2) {               \
      short8 bfr[4], afr[4];                                            \
      _Pragma("unroll") for (int cs = 0; cs < 4; ++cs)                  \
        bfr[cs] = FRAG2(&lT[BUF][1][0], wc * 64 + cs * 16 + c, kk2 * 4 + g); \
      _Pragma("unroll") for (int rs = 0; rs < 4; ++rs)                  \
        afr[rs] = FRAG2(&lT[BUF][0][0], wr * 64 + rs * 16 + c, kk2 * 4 + g); \
      _Pragma("unroll") for (int rs = 0; rs < 4; ++rs)                  \
        _Pragma("unroll") for (int cs = 0; cs < 4; ++cs)                \
          ACC[rs][cs] = __builtin_amdgcn_mfma_f32_16x16x32_bf16(        \
              afr[rs], bfr[cs], ACC[rs][cs], 0, 0, 0);                  \
    }                                                                   \
  } while (0)

  f32x4 accX[4][4];
  f32x4 accY[4][4];
  #pragma unroll
  for (int rs = 0; rs < 4; ++rs)
    #pragma unroll
    for (int cs = 0; cs < 4; ++cs) {
      accX[rs][cs] = (f32x4){0.f, 0.f, 0.f, 0.f};
      accY[rs][cs] = (f32x4){0.f, 0.f, 0.f, 0.f};
    }

  // Pipelined rounds: X-K0(buf0), X-K1(buf1), Y-K0(buf0), Y-K1(buf1).
  STAGE(0);
  __syncthreads();
  STAGE(1); COMPUTE(accX, 0); __syncthreads();
  STAGE(2); COMPUTE(accX, 1); __syncthreads();
  STAGE(3); COMPUTE(accY, 0); __syncthreads();
            COMPUTE(accY, 1);

  // ---- epilogue ----
  float sqxc[4], sqyc[4];
  #pragma unroll
  for (int cs = 0; cs < 4; ++cs) {
    sqxc[cs] = sqx[cj + cs * 16 + c];
    sqyc[cs] = sqy[cj + cs * 16 + c];
  }

  float p_acc = 0.f;
  float scol_acc[4] = {0.f, 0.f, 0.f, 0.f};   // per cs, band jb columns
  float tcol_acc[4] = {0.f, 0.f, 0.f, 0.f};

  #pragma unroll
  for (int rs = 0; rs < 4; ++rs) {
    const f32x4 sxr = *(const f32x4*)(sqx + ri + rs * 16 + g * 4);
    const f32x4 syr = *(const f32x4*)(sqy + ri + rs * 16 + g * 4);

    float sr_acc[4] = {0.f, 0.f, 0.f, 0.f};
    float tr_acc[4] = {0.f, 0.f, 0.f, 0.f};
    bool rowx = false, rowy = false;

    #pragma unroll
    for (int cs = 0; cs < 4; ++cs) {
      float ex[4], ey[4];
      #pragma unroll
      for (int tt = 0; tt < 4; ++tt) {
        ex[tt] = 2.f * accX[rs][cs][tt] - sxr[tt] - sqxc[cs];
        ey[tt] = 2.f * accY[rs][cs][tt] - syr[tt] - sqyc[cs];
      }
      const float mxx = fmaxf(fmaxf(ex[0], ex[1]), fmaxf(ex[2], ex[3]));
      const float mxy = fmaxf(fmaxf(ey[0], ey[1]), fmaxf(ey[2], ey[3]));
      const bool skipx = __all(mxx < SKIP_THR);
      const bool skipy = __all(mxy < SKIP_THR);
      if (skipx && skipy) continue;   // wave-uniform

      const int gc = cj + cs * 16 + c;
      float kx[4], ly[4];
      #pragma unroll
      for (int tt = 0; tt < 4; ++tt) {
        const int gr = ri + rs * 16 + g * 4 + tt;
        kx[tt] = skipx ? 0.f : ((gr == gc) ? 1.f : __expf(ex[tt]));
        ly[tt] = skipy ? 0.f : ((gr == gc) ? 1.f : __expf(ey[tt]));
      }
      if (!skipx) {
        rowx = true;
        float sc_ = 0.f;
        #pragma unroll
        for (int tt = 0; tt < 4; ++tt) { sr_acc[tt] += kx[tt]; sc_ += kx[tt]; }
        sc_ += __shfl_xor(sc_, 16, 64);   // reduce over g-lanes
        sc_ += __shfl_xor(sc_, 32, 64);
        scol_acc[cs] += sc_;
      }
      if (!skipy) {
        rowy = true;
        float tc_ = 0.f;
        #pragma unroll
        for (int tt = 0; tt < 4; ++tt) { tr_acc[tt] += ly[tt]; tc_ += ly[tt]; }
        tc_ += __shfl_xor(tc_, 16, 64);
        tc_ += __shfl_xor(tc_, 32, 64);
        tcol_acc[cs] += tc_;
      }
      if (!skipx && !skipy) {
        #pragma unroll
        for (int tt = 0; tt < 4; ++tt) p_acc += kx[tt] * ly[tt];
      }
    }

    if (rowx) {
      #pragma unroll
      for (int tt = 0; tt < 4; ++tt) {
        float sv = sr_acc[tt];
        #pragma unroll
        for (int off = 1; off < 16; off <<= 1) sv += __shfl_xor(sv, off, 64);
        if (c == 0) atomicAdd(&lds_sr[wr * 64 + rs * 16 + g * 4 + tt], sv);
      }
    }
    if (rowy) {
      #pragma unroll
      for (int tt = 0; tt < 4; ++tt) {
        float tv = tr_acc[tt];
        #pragma unroll
        for (int off = 1; off < 16; off <<= 1) tv += __shfl_xor(tv, off, 64);
        if (c == 0) atomicAdd(&lds_tr[wr * 64 + rs * 16 + g * 4 + tt], tv);
      }
    }
  }

  // Column sums (band jb rows via symmetry).
  if (g == 0) {
    #pragma unroll
    for (int cs = 0; cs < 4; ++cs) {
      atomicAdd(&lds_sc[wc * 64 + cs * 16 + c], scol_acc[cs]);
      atomicAdd(&lds_tc[wc * 64 + cs * 16 + c], tcol_acc[cs]);
    }
  }

  // Block-reduce P.
  #pragma unroll
  for (int off = 1; off < 64; off <<= 1) p_acc += __shfl_xor(p_acc, off, 64);
  if (lane == 0) red[wid] = p_acc;
  __syncthreads();

  // Band-keyed plain stores: row-part -> comb[ib][jb], col-part -> comb[jb][ib].
  if (tid < 128) {
    comb_s[((size_t)ib * NB + jb) * 128 + tid] = lds_sr[tid];
    comb_t[((size_t)ib * NB + jb) * 128 + tid] = lds_tr[tid];
    if (ib != jb) {
      comb_s[((size_t)jb * NB + ib) * 128 + tid] = lds_sc[tid];
      comb_t[((size_t)jb * NB + ib) * 128 + tid] = lds_tc[tid];
    }
  }
  if (tid == 0) {
    const float w = (ib == jb) ? 1.f : 2.f;
    P_part[bid] = w * (red[0] + red[1] + red[2] + red[3]);
  }
}

// 64 blocks x 512 threads: per band, fold 64 part-vectors -> row sums ->
// band partials (S, T, sum(s*t)). Fully coalesced, no atomics.
__global__ __launch_bounds__(512) void reduce1_kernel(
    const float* __restrict__ comb_s, const float* __restrict__ comb_t,
    float* __restrict__ band_acc)
{
  const int b   = blockIdx.x;
  const int tid = threadIdx.x;
  const int row = tid & 127;
  const int grp = tid >> 7;    // 0..3

  float sv = 0.f, tv = 0.f;
  for (int k = grp * 16; k < grp * 16 + 16; ++k) {
    sv += comb_s[((size_t)b * NB + k) * 128 + row];
    tv += comb_t[((size_t)b * NB + k) * 128 + row];
  }
  __shared__ float ls[4][128], lt[4][128];
  ls[grp][row] = sv;
  lt[grp][row] = tv;
  __syncthreads();

  __shared__ float r2[2][3];
  if (tid < 128) {
    float S = ls[0][row] + ls[1][row] + ls[2][row] + ls[3][row];
    float T = lt[0][row] + lt[1][row] + lt[2][row] + lt[3][row];
    float C = S * T;
    #pragma unroll
    for (int off = 1; off < 64; off <<= 1) {
      S += __shfl_xor(S, off, 64);
      T += __shfl_xor(T, off, 64);
      C += __shfl_xor(C, off, 64);
    }
    if ((tid & 63) == 0) { r2[tid >> 6][0] = S; r2[tid >> 6][1] = T; r2[tid >> 6][2] = C; }
  }
  __syncthreads();
  if (tid == 0) {
    band_acc[b * 4 + 0] = r2[0][0] + r2[1][0];
    band_acc[b * 4 + 1] = r2[0][1] + r2[1][1];
    band_acc[b * 4 + 2] = r2[0][2] + r2[1][2];
  }
}

// One block: sum band partials + P parts, final formula in double.
__global__ __launch_bounds__(256) void reduce2_kernel(
    const float* __restrict__ band_acc, const float* __restrict__ P_part,
    float* __restrict__ out)
{
  const int tid = threadIdx.x;
  float S = 0.f, T = 0.f, C = 0.f, P = 0.f;
  if (tid < NB) {
    S = band_acc[tid * 4 + 0];
    T = band_acc[tid * 4 + 1];
    C = band_acc[tid * 4 + 2];
  }
  for (int i = tid; i < NTRI; i += 256) P += P_part[i];
  #pragma unroll
  for (int off = 1; off < 64; off <<= 1) {
    S += __shfl_xor(S, off, 64);
    T += __shfl_xor(T, off, 64);
    C += __shfl_xor(C, off, 64);
    P += __shfl_xor(P, off, 64);
  }
  __shared__ float r[4][4];
  const int w = tid >> 6;
  if ((tid & 63) == 0) { r[w][0] = S; r[w][1] = T; r[w][2] = C; r[w][3] = P; }
  __syncthreads();
  if (tid == 0) {
    const double St = (double)r[0][0] + r[1][0] + r[2][0] + r[3][0];
    const double Tt = (double)r[0][1] + r[1][1] + r[2][1] + r[3][1];
    const double Ct = (double)r[0][2] + r[1][2] + r[2][2] + r[3][2];
    const double Pt = (double)r[0][3] + r[1][3] + r[2][3] + r[3][3];
    const double m  = (double)MM;
    const double num = Pt - (2.0 / m) * Ct + (St * Tt) / (m * m);
    out[0] = (float)(num / ((m - 1.0) * (m - 1.0)));
  }
}

extern "C" void kernel_launch(void* const* d_in, const int* in_sizes, int n_in,
                              void* d_out, int out_size, void* d_ws, size_t ws_size,
                              hipStream_t stream) {
  const float* x = (const float*)d_in[0];
  const float* y = (const float*)d_in[1];

  char* ws = (char*)d_ws;
  u16*   xb       = (u16*)ws;                                      // 2 MB
  u16*   yb       = (u16*)(ws + (size_t)2 * 1024 * 1024);          // 2 MB
  float* sqx      = (float*)(ws + (size_t)4 * 1024 * 1024);        // 32 KB
  float* sqy      = sqx + MM;                                      // 32 KB
  float* comb_s   = sqy + MM;                                      // 2 MB
  float* comb_t   = comb_s + (size_t)NB * NB * 128;                // 2 MB
  float* P_part   = comb_t + (size_t)NB * NB * 128;                // 8.3 KB
  float* band_acc = P_part + NTRI;                                 // 1 KB

  convert_kernel<<<MM / 8, 256, 0, stream>>>(x, y, xb, yb, sqx, sqy);

  hsic_pair_kernel<<<NTRI, 256, 0, stream>>>(xb, yb, sqx, sqy, comb_s, comb_t, P_part);

  reduce1_kernel<<<NB, 512, 0, stream>>>(comb_s, comb_t, band_acc);
  reduce2_kernel<<<1, 256, 0, stream>>>(band_acc, P_part, (float*)d_out);
}